// Round 11
// baseline (494.616 us; speedup 1.0000x reference)
//
#include <hip/hip_runtime.h>
#include <hip/hip_fp16.h>

#define B_ 16384
#define T_ 128
#define E_ 32
#define H_ 128
#define G3_ 384
#define V_ 30001
#define D_ 128
#define C_ 3

#define LOG2E 1.44269504088896340736f

typedef _Float16 f16;
typedef f16 f16x4 __attribute__((ext_vector_type(4)));
typedef f16 f16x8 __attribute__((ext_vector_type(8)));
typedef float f32x4 __attribute__((ext_vector_type(4)));
typedef unsigned int u32;

// ---- LDS layout (bytes), 256-thread block (4 waves), 64 batch rows ----
// UT: U^T pre-scaled f16, rows = 384 gate-cols, pitch 272 (128 f16 + pad).
// Per-wave slab: h scratch [16][272] then token offsets [129][16] u32.
// Head reuses slab as f32 dbuf [16 rows][132] (pitch 528).
#define UTPITCH   272
#define UT_BYTES  (G3_ * UTPITCH)          // 104448
#define SLAB_SZ   12608                    // 4352 (h) + 8256 (tok)
#define HS_OFF    0
#define TK_OFF    4352
#define LDS_TOTAL (UT_BYTES + 4 * SLAB_SZ) // 154880 <= 160K

__device__ __forceinline__ float frcp_(float x)  { return __builtin_amdgcn_rcpf(x); }
__device__ __forceinline__ float fexp2_(float x) { return __builtin_amdgcn_exp2f(x); }

// ---------------- Kernel 1: pre-scaled, lane-contiguous PERMUTED table ----------------
// For gate-col c = 16*t8 + 4*q + i and slot s (0=z,1=r scaled by -log2e with b1
// folded; 2=h scaled by +2log2e): pos = ((s*4+q)*8 + t8)*4 + i. Row = 384 f16 = 768 B.
#define K1_ROWS 8
__global__ __launch_bounds__(384) void embw_kernel(
    const float* __restrict__ emb,   // [V][32]
    const float* __restrict__ W,     // [32][384]
    const float* __restrict__ b,     // [2][384]
    f16* __restrict__ embW)          // [V][384] f16 permuted, pre-scaled
{
    __shared__ float sW[E_][G3_];
    __shared__ float sE[K1_ROWS][E_];
    const int g = threadIdx.x;           // 0..383 = slot*128 + c
    #pragma unroll
    for (int e = 0; e < E_; ++e) sW[e][g] = W[e * G3_ + g];
    const int v0 = blockIdx.x * K1_ROWS;
    for (int idx = g; idx < K1_ROWS * E_; idx += 384) {
        int rr = idx >> 5, ee = idx & 31;
        int v = v0 + rr;
        sE[rr][ee] = (v < V_) ? emb[v * E_ + ee] : 0.f;
    }
    __syncthreads();
    const float bg = b[g] + ((g < 256) ? b[G3_ + g] : 0.f);
    const float sc = (g >= 256) ? (2.f * LOG2E) : (-LOG2E);
    const int slot = g >> 7, c = g & 127;
    const int t8 = c >> 4, q = (c >> 2) & 3, i = c & 3;
    const int pos = ((slot * 4 + q) * 8 + t8) * 4 + i;
    #pragma unroll
    for (int rr = 0; rr < K1_ROWS; ++rr) {
        int v = v0 + rr;
        if (v >= V_) break;
        float acc = bg;
        #pragma unroll
        for (int e = 0; e < E_; ++e) acc = fmaf(sE[rr][e], sW[e][g], acc);
        embW[(size_t)v * G3_ + pos] = (f16)(acc * sc);
    }
}

// ---------------- Kernel 2: barrier-free wave-private GRU, U^T in LDS ----------------
// 256 blocks x 256 threads (4 waves, 1/SIMD). Block owns 64 rows; wave w owns
// rows [16w,16w+16) AND all 128 h-cols -> h never crosses waves; no barriers
// in the T-loop (DS ops are in-order per wave). U^T staged once in LDS,
// shared read-only by the 4 waves.
// MFMA 16x16x32 f16 (transposed output), per tile t8 (16 gate-cols):
//   A (LDS UT): lane l holds sc*U[kt*32+q*8+j][gt*128 + 16*t8 + cl]
//   B (LDS h scratch): lane l holds h[batch=cl][kt*32+q*8+j]
//   D: lane l reg i -> (gate-col 16*t8+4q+i, batch cl)
__global__ __launch_bounds__(256, 1) void gru_mfma_kernel(
    const int*   __restrict__ tokens,  // [B][T]
    const f16*   __restrict__ embW,    // [V][384] f16 permuted, pre-scaled
    const float* __restrict__ U,       // [128][384]
    const float* __restrict__ b,       // [2][384]
    const float* __restrict__ W1,      // [128][128]
    const float* __restrict__ b1,      // [128]
    const float* __restrict__ Wout,    // [128][3]
    const float* __restrict__ bout,    // [3]
    float* __restrict__ out)           // [B][3]
{
    __shared__ char lds[LDS_TOTAL];
    const int tid = threadIdx.x;
    const int w   = tid >> 6;       // wave -> rows [16w,16w+16)
    const int l   = tid & 63;
    const int cl  = l & 15;         // batch row within wave
    const int q   = l >> 4;         // 0..3
    const int R0  = blockIdx.x * 64;

    // ---- stage U^T (pre-scaled) into LDS, coalesced global reads ----
    for (int idx = tid; idx < G3_ * H_; idx += 256) {
        const int c = idx % G3_, k = idx / G3_;
        const float sc = (c >= 256) ? (2.f * LOG2E) : (-LOG2E);
        *(f16*)(&lds[c * UTPITCH + k * 2]) = (f16)(U[(size_t)k * G3_ + c] * sc);
    }
    // ---- stage token byte-offsets (tok*768) into per-wave slabs [t][16] ----
    for (int idx = tid; idx < 64 * T_; idx += 256) {
        const int r = idx >> 7, t = idx & 127;
        const u32 tok = (u32)tokens[(size_t)(R0 + r) * T_ + t];
        *(u32*)(&lds[UT_BYTES + (r >> 4) * SLAB_SZ + TK_OFF + t * 64 + (r & 15) * 4])
            = tok * 768u;
    }
    if (tid < 64)   // zero the t=128 prefetch row
        *(u32*)(&lds[UT_BYTES + (tid >> 4) * SLAB_SZ + TK_OFF + 128 * 64 + (tid & 15) * 4]) = 0u;
    // ---- zero h scratches ----
    for (int idx = tid; idx < 4 * 1088; idx += 256)
        *(float*)(&lds[UT_BYTES + (idx / 1088) * SLAB_SZ + HS_OFF + (idx % 1088) * 4]) = 0.f;

    __syncthreads();   // the only block-wide barrier before the epilogue

    char* slab  = &lds[UT_BYTES + w * SLAB_SZ];
    char* hs    = slab + HS_OFF;
    const char* tokp = slab + TK_OFF;
    const char* embWb = (const char*)embW;

    // h-gate recurrent bias per tile (b is zeros here; honored anyway)
    f32x4 bhr[8];
    #pragma unroll
    for (int t8 = 0; t8 < 8; ++t8)
        #pragma unroll
        for (int i = 0; i < 4; ++i)
            bhr[t8][i] = 2.f * LOG2E * b[G3_ + 256 + 16 * t8 + 4 * q + i];

    float hreg[8][4];
    #pragma unroll
    for (int t8 = 0; t8 < 8; ++t8)
        #pragma unroll
        for (int i = 0; i < 4; ++i) hreg[t8][i] = 0.f;

    // prefetch t=0 gathers: 3 slots x 4 x 16B, lane-contiguous (permuted table)
    u32 offc = *(const u32*)(tokp + cl * 4);
    f16x8 xgC[3][4];
    #pragma unroll
    for (int s = 0; s < 3; ++s) {
        const char* p = embWb + offc + ((s * 4 + q) << 6);
        #pragma unroll
        for (int u = 0; u < 4; ++u) xgC[s][u] = *(const f16x8*)(p + u * 16);
    }

    for (int t = 0; t < T_; ++t) {
        // ---- B-fragments: h(t) from own scratch (in-order DS per wave) ----
        f16x8 bf[4];
        #pragma unroll
        for (int kt = 0; kt < 4; ++kt)
            bf[kt] = *(const f16x8*)(hs + cl * UTPITCH + kt * 64 + q * 16);

        // ---- issue next-step gathers early (covered by this step's compute) ----
        const u32 offn = *(const u32*)(tokp + (t + 1) * 64 + cl * 4);
        f16x8 xgN[3][4];
        #pragma unroll
        for (int s = 0; s < 3; ++s) {
            const char* p = embWb + offn + ((s * 4 + q) << 6);
            #pragma unroll
            for (int u = 0; u < 4; ++u) xgN[s][u] = *(const f16x8*)(p + u * 16);
        }

        const int abase = cl * UTPITCH + q * 16;

        // ---- per 16-col tile: 12 MFMAs + gates + h write ----
        #pragma unroll
        for (int t8 = 0; t8 < 8; ++t8) {
            const int u = t8 >> 1, hh4 = (t8 & 1) << 2;
            f32x4 az, ar;
            #pragma unroll
            for (int i = 0; i < 4; ++i) {
                az[i] = (float)xgC[0][u][hh4 + i];
                ar[i] = (float)xgC[1][u][hh4 + i];
            }
            f32x4 ah = bhr[t8];
            #pragma unroll
            for (int kt = 0; kt < 4; ++kt) {
                const f16x8 afz = *(const f16x8*)(&lds[(0 * 128 + 16 * t8) * UTPITCH + abase + kt * 64]);
                const f16x8 afr = *(const f16x8*)(&lds[(1 * 128 + 16 * t8) * UTPITCH + abase + kt * 64]);
                const f16x8 afh = *(const f16x8*)(&lds[(2 * 128 + 16 * t8) * UTPITCH + abase + kt * 64]);
                az = __builtin_amdgcn_mfma_f32_16x16x32_f16(afz, bf[kt], az, 0, 0, 0);
                ar = __builtin_amdgcn_mfma_f32_16x16x32_f16(afr, bf[kt], ar, 0, 0, 0);
                ah = __builtin_amdgcn_mfma_f32_16x16x32_f16(afh, bf[kt], ah, 0, 0, 0);
            }
            f16x4 hv4;
            #pragma unroll
            for (int i = 0; i < 4; ++i) {
                const float z  = frcp_(1.f + fexp2_(az[i]));
                const float r  = frcp_(1.f + fexp2_(ar[i]));
                const float xh = (float)xgC[2][u][hh4 + i];
                const float hh = fmaf(-2.f, frcp_(1.f + fexp2_(fmaf(r, ah[i], xh))), 1.f);
                const float hv = hreg[t8][i];
                float nv = fmaf(z, hv - hh, hh);
                nv = (offc != 0u) ? nv : hv;
                hreg[t8][i] = nv;
                hv4[i] = (f16)nv;
            }
            // h(t+1)[cl][16*t8+4q .. +3]: one b64, conflict-free spread
            *(f16x4*)(hs + cl * UTPITCH + t8 * 32 + q * 8) = hv4;
        }

        offc = offn;
        #pragma unroll
        for (int s = 0; s < 3; ++s)
            #pragma unroll
            for (int u = 0; u < 4; ++u) xgC[s][u] = xgN[s][u];
    }

    // ---- head: d^T = W1^T @ h^T (swish), all 128 d-cols per wave ----
    {
        // read final h B-frags FIRST (dbuf will overwrite the scratch)
        f16x8 bf[4];
        #pragma unroll
        for (int kt = 0; kt < 4; ++kt)
            bf[kt] = *(const f16x8*)(hs + cl * UTPITCH + kt * 64 + q * 16);
        asm volatile("s_waitcnt lgkmcnt(0)" ::: "memory");

        #pragma unroll
        for (int t8 = 0; t8 < 8; ++t8) {
            f32x4 dacc;
            #pragma unroll
            for (int i = 0; i < 4; ++i) dacc[i] = b1[16 * t8 + 4 * q + i];
            #pragma unroll
            for (int kt = 0; kt < 4; ++kt) {
                f16x8 wf;
                #pragma unroll
                for (int j = 0; j < 8; ++j)
                    wf[j] = (f16)W1[(size_t)(kt * 32 + q * 8 + j) * D_ + 16 * t8 + cl];
                dacc = __builtin_amdgcn_mfma_f32_16x16x32_f16(wf, bf[kt], dacc, 0, 0, 0);
            }
            f32x4 sw;
            #pragma unroll
            for (int i = 0; i < 4; ++i) {
                const float v = dacc[i];
                sw[i] = v * frcp_(1.f + fexp2_(-LOG2E * v));
            }
            // dbuf[cl][16*t8+4q .. +3] f32, pitch 528 (reuses slab)
            *(f32x4*)(slab + cl * 528 + (16 * t8 + 4 * q) * 4) = sw;
        }
        asm volatile("s_waitcnt lgkmcnt(0)" ::: "memory");
    }

    // ---- logits + softmax: 48 lanes per wave = 16 rows x 3 classes ----
    if (l < 48) {
        const int row = l & 15, ci = l >> 4;
        float acc = bout[ci];
        #pragma unroll 4
        for (int k = 0; k < D_; ++k)
            acc = fmaf(*(const float*)(slab + row * 528 + k * 4), Wout[k * 3 + ci], acc);
        const float v0 = __shfl(acc, row);
        const float v1 = __shfl(acc, row + 16);
        const float v2 = __shfl(acc, row + 32);
        const float mx = fmaxf(v0, fmaxf(v1, v2));
        const float e0 = fexp2_(LOG2E * (v0 - mx));
        const float e1 = fexp2_(LOG2E * (v1 - mx));
        const float e2 = fexp2_(LOG2E * (v2 - mx));
        const float inv = frcp_(e0 + e1 + e2);
        const float mine = (ci == 0) ? e0 : (ci == 1) ? e1 : e2;
        out[(size_t)(R0 + w * 16 + row) * 3 + ci] = mine * inv;
    }
}

extern "C" void kernel_launch(void* const* d_in, const int* in_sizes, int n_in,
                              void* d_out, int out_size, void* d_ws, size_t ws_size,
                              hipStream_t stream) {
    (void)in_sizes; (void)n_in; (void)out_size; (void)ws_size;
    const int*   tokens = (const int*)d_in[0];
    const float* emb    = (const float*)d_in[1];
    const float* W      = (const float*)d_in[2];
    const float* U      = (const float*)d_in[3];
    const float* b      = (const float*)d_in[4];
    const float* W1     = (const float*)d_in[5];
    const float* b1     = (const float*)d_in[6];
    const float* Wout   = (const float*)d_in[7];
    const float* bout   = (const float*)d_in[8];
    float* out  = (float*)d_out;
    f16*   embW = (f16*)d_ws;   // [V][384] f16 (permuted) = 23 MB scratch

    hipLaunchKernelGGL(embw_kernel, dim3((V_ + K1_ROWS - 1) / K1_ROWS), dim3(384), 0, stream,
                       emb, W, b, embW);
    hipLaunchKernelGGL(gru_mfma_kernel, dim3(B_ / 64), dim3(256), 0, stream,
                       tokens, embW, U, b, W1, b1, Wout, bout, out);
}

// Round 12
// 365.898 us; speedup vs baseline: 1.3518x; 1.3518x over previous
//
#include <hip/hip_runtime.h>
#include <hip/hip_fp16.h>

#define B_ 16384
#define T_ 128
#define E_ 32
#define H_ 128
#define G3_ 384
#define V_ 30001
#define D_ 128
#define C_ 3

#define LOG2E 1.44269504088896340736f

typedef _Float16 f16;
typedef f16 f16x4 __attribute__((ext_vector_type(4)));
typedef f16 f16x8 __attribute__((ext_vector_type(8)));
typedef float f32x4 __attribute__((ext_vector_type(4)));
typedef unsigned int u32;
typedef u32 u32x4 __attribute__((ext_vector_type(4)));

// ---- LDS layout (bytes), 512-thread block, 16 batch rows ----
// h buffers: [16 rows][256 B], XOR-swizzled: byte(row,col) = row*256 + (col*2 ^ ((row&7)<<4))
#define H0_OFF   0
#define H1_OFF   4096
#define TOK_OFF  8192                // u32 byte-offsets, [t=129][r=16] (t=128 zeroed)
#define DBUF_OFF 16448               // head dbuf f32 [16][132]
#define LDS_TOTAL 24896

__device__ __forceinline__ float frcp_(float x)  { return __builtin_amdgcn_rcpf(x); }
__device__ __forceinline__ float fexp2_(float x) { return __builtin_amdgcn_exp2f(x); }

// lgkm-only barrier: orders LDS h traffic; leaves global prefetch in flight
// (compiler inserts counted vmcnt before the USE of the loaded regs).
#define BAR_LGKM() asm volatile("s_waitcnt lgkmcnt(0)\n\ts_barrier" ::: "memory")

// ---------------- Kernel 1: packed, PRE-SCALED table ----------------
// embW_p[v][c][slot] f16; slot 0=z,1=r (x -log2e, b0+b1 folded),
// 2=h (x +2log2e, b0 folded; b1_h stays in the kernel), 3=pad.
#define K1_ROWS 8
__global__ __launch_bounds__(384) void embw_kernel(
    const float* __restrict__ emb,   // [V][32]
    const float* __restrict__ W,     // [32][384]
    const float* __restrict__ b,     // [2][384]
    f16* __restrict__ embW)          // [V][128][4] f16
{
    __shared__ float sW[E_][G3_];
    __shared__ float sE[K1_ROWS][E_];
    const int g = threadIdx.x;           // 0..383 (= slot*128 + c)
    #pragma unroll
    for (int e = 0; e < E_; ++e) sW[e][g] = W[e * G3_ + g];
    const int v0 = blockIdx.x * K1_ROWS;
    for (int idx = g; idx < K1_ROWS * E_; idx += 384) {
        int rr = idx >> 5, ee = idx & 31;
        int v = v0 + rr;
        sE[rr][ee] = (v < V_) ? emb[v * E_ + ee] : 0.f;
    }
    __syncthreads();
    const float bg = b[g] + ((g < 256) ? b[G3_ + g] : 0.f);
    const int c = g & 127, slot = g >> 7;
    const float sc = (slot == 2) ? (2.f * LOG2E) : (-LOG2E);
    #pragma unroll
    for (int rr = 0; rr < K1_ROWS; ++rr) {
        int v = v0 + rr;
        if (v >= V_) break;
        float acc = bg;
        #pragma unroll
        for (int e = 0; e < E_; ++e) acc = fmaf(sE[rr][e], sW[e][g], acc);
        embW[(size_t)v * 512 + c * 4 + slot] = (f16)(acc * sc);
    }
}

// ---------------- Kernel 2: GRU, 8 waves x 16 cols, U persistent in VGPRs ----------------
// 1024 blocks x 512 threads. Block owns 16 batch rows; wave w owns h-cols
// [16w,16w+16). Per lane: col = w*16+cl, rows 4q..4q+3. U slice (12 f16x8 = 48
// VGPR) persistent. h XOR-swizzled in LDS (write b16 x4, read b128 swizzled).
// z/r accumulators init from converted x (C-operand folding); combined-rcp for
// the z,r sigmoid pair; lgkm-only step barrier.
// MFMA 16x16x32 f16 layouts (verified rounds 2-10):
//   A: lane l holds A[l&15][(l>>4)*8 + j]
//   B: lane l holds B[(l>>4)*8 + j][l&15]
//   C/D: lane l, reg i -> row=(l>>4)*4+i, col=l&15
__global__ __launch_bounds__(512, 4) void gru_mfma_kernel(
    const int*   __restrict__ tokens,  // [B][T]
    const f16*   __restrict__ embW,    // [V][128][4] f16 packed, pre-scaled
    const float* __restrict__ U,       // [128][384]
    const float* __restrict__ b,       // [2][384]
    const float* __restrict__ W1,      // [128][128]
    const float* __restrict__ b1,      // [128]
    const float* __restrict__ Wout,    // [128][3]
    const float* __restrict__ bout,    // [3]
    float* __restrict__ out)           // [B][3]
{
    __shared__ char lds[LDS_TOTAL];
    const int tid = threadIdx.x;
    const int w   = tid >> 6;       // wave = 16-col group, 0..7
    const int l   = tid & 63;
    const int cl  = l & 15;
    const int q   = l >> 4;         // 0..3
    const int R0  = blockIdx.x * 16;
    const int col = w * 16 + cl;    // this lane's h column

    // ---- stage token BYTE OFFSETS, transposed [t][r] (tok*1024 = row bytes) ----
    for (int idx = tid; idx < 16 * T_; idx += 512) {
        int r = idx >> 7, t = idx & 127;
        u32 tok = (u32)tokens[(size_t)(R0 + r) * T_ + t];
        *(u32*)(&lds[TOK_OFF + t * 64 + r * 4]) = tok * 1024u;
    }
    if (tid < 16)   // zero the t=128 prefetch row (branch-free last iteration)
        *(u32*)(&lds[TOK_OFF + 128 * 64 + tid * 4]) = 0u;
    // ---- zero h buffer 0 ----
    for (int idx = tid; idx < 1024; idx += 512)
        ((float*)(lds + H0_OFF))[idx] = 0.f;

    // ---- persistent U fragments, pre-scaled (one-time strided global read) ----
    // Bf[gate][kt]: lane holds sc(gate) * U[kt*32 + q*8 + j][gate*128 + col]
    f16x8 Bf[3][4];
    #pragma unroll
    for (int gt = 0; gt < 3; ++gt) {
        const float sc = (gt == 2) ? (2.f * LOG2E) : (-LOG2E);
        const int n = gt * 128 + col;
        #pragma unroll
        for (int kt = 0; kt < 4; ++kt) {
            const int k0 = kt * 32 + q * 8;
            f16x8 fr;
            #pragma unroll
            for (int j = 0; j < 8; ++j)
                fr[j] = (f16)(U[(size_t)(k0 + j) * G3_ + n] * sc);
            Bf[gt][kt] = fr;
        }
    }

    // h-gate recurrent bias (sits inside r*(.), can't fold into table)
    const float bhs = 2.f * LOG2E * b[G3_ + 256 + col];
    const f32x4 bh4 = {bhs, bhs, bhs, bhs};

    float hreg[4];
    #pragma unroll
    for (int i = 0; i < 4; ++i) hreg[i] = 0.f;

    __syncthreads();

    const char* embWb = (const char*)embW;
    const int col8 = col * 8;

    // prefetch t=0
    u32x4 offc = *(const u32x4*)(&lds[TOK_OFF + q * 16]);
    f16x4 xvc[4];
    #pragma unroll
    for (int i = 0; i < 4; ++i)
        xvc[i] = *(const f16x4*)(embWb + offc[i] + col8);

    int cur = 0;
    for (int t = 0; t < T_; ++t) {
        const char* hb = lds + (cur ? H1_OFF : H0_OFF);
        char*       hn = lds + (cur ? H0_OFF : H1_OFF);

        // ---- issue prefetch for t+1 (branch-free; row 128 is zeroed) ----
        const u32x4 offn = *(const u32x4*)(&lds[TOK_OFF + (t + 1) * 64 + q * 16]);
        f16x4 xvn[4];
        #pragma unroll
        for (int i = 0; i < 4; ++i)
            xvn[i] = *(const f16x4*)(embWb + offn[i] + col8);

        // ---- rec = h @ U (pre-scaled), swizzled A reads, C-operand = x ----
        f16x8 af[4];
        #pragma unroll
        for (int kt = 0; kt < 4; ++kt) {
            const int chunk = (kt * 64 + q * 16) ^ ((cl & 7) << 4);
            af[kt] = *(const f16x8*)(hb + cl * 256 + chunk);
        }
        f32x4 xz4, xr4;
        #pragma unroll
        for (int i = 0; i < 4; ++i) {
            xz4[i] = (float)xvc[i][0];
            xr4[i] = (float)xvc[i][1];
        }
        f32x4 accz = __builtin_amdgcn_mfma_f32_16x16x32_f16(af[0], Bf[0][0], xz4, 0, 0, 0);
        f32x4 accr = __builtin_amdgcn_mfma_f32_16x16x32_f16(af[0], Bf[1][0], xr4, 0, 0, 0);
        f32x4 acch = __builtin_amdgcn_mfma_f32_16x16x32_f16(af[0], Bf[2][0], bh4, 0, 0, 0);
        accz = __builtin_amdgcn_mfma_f32_16x16x32_f16(af[1], Bf[0][1], accz, 0, 0, 0);
        accr = __builtin_amdgcn_mfma_f32_16x16x32_f16(af[1], Bf[1][1], accr, 0, 0, 0);
        acch = __builtin_amdgcn_mfma_f32_16x16x32_f16(af[1], Bf[2][1], acch, 0, 0, 0);
        accz = __builtin_amdgcn_mfma_f32_16x16x32_f16(af[2], Bf[0][2], accz, 0, 0, 0);
        accr = __builtin_amdgcn_mfma_f32_16x16x32_f16(af[2], Bf[1][2], accr, 0, 0, 0);
        acch = __builtin_amdgcn_mfma_f32_16x16x32_f16(af[2], Bf[2][2], acch, 0, 0, 0);
        accz = __builtin_amdgcn_mfma_f32_16x16x32_f16(af[3], Bf[0][3], accz, 0, 0, 0);
        accr = __builtin_amdgcn_mfma_f32_16x16x32_f16(af[3], Bf[1][3], accr, 0, 0, 0);
        acch = __builtin_amdgcn_mfma_f32_16x16x32_f16(af[3], Bf[2][3], acch, 0, 0, 0);

        // ---- gates: combined-rcp sigmoid pair + exp2-direct tanh ----
        #pragma unroll
        for (int i = 0; i < 4; ++i) {
            const float ez = fexp2_(accz[i]);
            const float er = fexp2_(accr[i]);
            const float pz = 1.f + ez;
            const float pr = 1.f + er;
            const float inv = frcp_(pz * pr);
            const float z  = pr * inv;           // = 1/(1+ez)
            const float r  = pz * inv;           // = 1/(1+er)
            const float hh = fmaf(-2.f, frcp_(1.f + fexp2_(fmaf(r, acch[i], (float)xvc[i][2]))), 1.f);
            const float hv = hreg[i];
            float nv = fmaf(z, hv - hh, hh);
            nv = (offc[i] != 0u) ? nv : hv;
            hreg[i] = nv;
            const int row = 4 * q + i;
            *(f16*)(hn + row * 256 + ((col * 2) ^ ((row & 7) << 4))) = (f16)nv;
        }
        BAR_LGKM();
        cur ^= 1;
        offc = offn;
        #pragma unroll
        for (int i = 0; i < 4; ++i) xvc[i] = xvn[i];
    }
    // T_=128 even -> final h is in buffer 0

    // ---- head: d = swish(h @ W1 + b1), one 16-col tile per wave ----
    {
        f16x8 Wf[4];
        #pragma unroll
        for (int kt = 0; kt < 4; ++kt) {
            const int k0 = kt * 32 + q * 8;
            f16x8 fr;
            #pragma unroll
            for (int j = 0; j < 8; ++j)
                fr[j] = (f16)W1[(size_t)(k0 + j) * D_ + col];
            Wf[kt] = fr;
        }
        const char* hb = lds + H0_OFF;
        const float bd = b1[col];
        f32x4 dacc = {bd, bd, bd, bd};
        #pragma unroll
        for (int kt = 0; kt < 4; ++kt) {
            const int chunk = (kt * 64 + q * 16) ^ ((cl & 7) << 4);
            const f16x8 af = *(const f16x8*)(hb + cl * 256 + chunk);
            dacc = __builtin_amdgcn_mfma_f32_16x16x32_f16(af, Wf[kt], dacc, 0, 0, 0);
        }
        #pragma unroll
        for (int i = 0; i < 4; ++i) {
            const float v = dacc[i];
            const float sw = v * frcp_(1.f + fexp2_(-LOG2E * v));
            *(float*)(&lds[DBUF_OFF + (4 * q + i) * 528 + col * 4]) = sw;
        }
    }
    __syncthreads();

    // ---- logits + softmax: wave 0, 48 lanes = 16 rows x 3 classes ----
    if (w == 0 && l < 48) {
        const int row = l & 15, ci = l >> 4;
        float acc = bout[ci];
        #pragma unroll 4
        for (int k = 0; k < D_; ++k)
            acc = fmaf(*(const float*)(&lds[DBUF_OFF + row * 528 + k * 4]),
                       Wout[k * 3 + ci], acc);
        const float v0 = __shfl(acc, row);
        const float v1 = __shfl(acc, row + 16);
        const float v2 = __shfl(acc, row + 32);
        const float mx = fmaxf(v0, fmaxf(v1, v2));
        const float e0 = fexp2_(LOG2E * (v0 - mx));
        const float e1 = fexp2_(LOG2E * (v1 - mx));
        const float e2 = fexp2_(LOG2E * (v2 - mx));
        const float inv = frcp_(e0 + e1 + e2);
        const float mine = (ci == 0) ? e0 : (ci == 1) ? e1 : e2;
        out[(size_t)(R0 + row) * 3 + ci] = mine * inv;
    }
}

extern "C" void kernel_launch(void* const* d_in, const int* in_sizes, int n_in,
                              void* d_out, int out_size, void* d_ws, size_t ws_size,
                              hipStream_t stream) {
    (void)in_sizes; (void)n_in; (void)out_size; (void)ws_size;
    const int*   tokens = (const int*)d_in[0];
    const float* emb    = (const float*)d_in[1];
    const float* W      = (const float*)d_in[2];
    const float* U      = (const float*)d_in[3];
    const float* b      = (const float*)d_in[4];
    const float* W1     = (const float*)d_in[5];
    const float* b1     = (const float*)d_in[6];
    const float* Wout   = (const float*)d_in[7];
    const float* bout   = (const float*)d_in[8];
    float* out  = (float*)d_out;
    f16*   embW = (f16*)d_ws;   // [V][128][4] f16 = 30.7 MB scratch

    hipLaunchKernelGGL(embw_kernel, dim3((V_ + K1_ROWS - 1) / K1_ROWS), dim3(384), 0, stream,
                       emb, W, b, embW);
    hipLaunchKernelGGL(gru_mfma_kernel, dim3(B_ / 16), dim3(512), 0, stream,
                       tokens, embW, U, b, W1, b1, Wout, bout, out);
}

// Round 13
// 355.954 us; speedup vs baseline: 1.3895x; 1.0279x over previous
//
#include <hip/hip_runtime.h>
#include <hip/hip_fp16.h>

#define B_ 16384
#define T_ 128
#define E_ 32
#define H_ 128
#define G3_ 384
#define V_ 30001
#define D_ 128
#define C_ 3

#define LOG2E 1.44269504088896340736f

typedef _Float16 f16;
typedef f16 f16x4 __attribute__((ext_vector_type(4)));
typedef f16 f16x8 __attribute__((ext_vector_type(8)));
typedef float f32x4 __attribute__((ext_vector_type(4)));
typedef unsigned int u32;
typedef u32 u32x4 __attribute__((ext_vector_type(4)));

// ---- LDS layout (bytes), 512-thread block, 16 batch rows ----
// h buffers: [16 rows][256 B], XOR-swizzled: byte(row,col) = row*256 + (col*2 ^ ((row&7)<<4))
#define H0_OFF   0
#define H1_OFF   4096
#define TOK_OFF  8192                // u32 byte-offsets, [t=129][r=16] (t=128 zeroed)
#define DBUF_OFF 16448               // head dbuf f32 [16][132]
#define LDS_TOTAL 24896

__device__ __forceinline__ float frcp_(float x)  { return __builtin_amdgcn_rcpf(x); }
__device__ __forceinline__ float fexp2_(float x) { return __builtin_amdgcn_exp2f(x); }

// lgkm-only barrier: orders LDS h traffic; leaves global prefetch in flight.
#define BAR_LGKM() asm volatile("s_waitcnt lgkmcnt(0)\n\ts_barrier" ::: "memory")

// ---------------- Kernel 1: packed EXP-SPACE table ----------------
// embW_p[v][c][slot] f16:
//   slot 0 = 2^(-log2e*(xz + b0z + b1z))   (z gate, fully bias-folded)
//   slot 1 = 2^(-log2e*(xr + b0r + b1r))   (r gate, fully bias-folded)
//   slot 2 = 2^(+2log2e*(xh + b0h))        (h gate; b1h stays in-kernel)
//   slot 3 = pad
#define K1_ROWS 8
__global__ __launch_bounds__(384) void embw_kernel(
    const float* __restrict__ emb,   // [V][32]
    const float* __restrict__ W,     // [32][384]
    const float* __restrict__ b,     // [2][384]
    f16* __restrict__ embW)          // [V][128][4] f16
{
    __shared__ float sW[E_][G3_];
    __shared__ float sE[K1_ROWS][E_];
    const int g = threadIdx.x;           // 0..383 (= slot*128 + c)
    #pragma unroll
    for (int e = 0; e < E_; ++e) sW[e][g] = W[e * G3_ + g];
    const int v0 = blockIdx.x * K1_ROWS;
    for (int idx = g; idx < K1_ROWS * E_; idx += 384) {
        int rr = idx >> 5, ee = idx & 31;
        int v = v0 + rr;
        sE[rr][ee] = (v < V_) ? emb[v * E_ + ee] : 0.f;
    }
    __syncthreads();
    const float bg = b[g] + ((g < 256) ? b[G3_ + g] : 0.f);
    const int c = g & 127, slot = g >> 7;
    const float sc = (slot == 2) ? (2.f * LOG2E) : (-LOG2E);
    #pragma unroll
    for (int rr = 0; rr < K1_ROWS; ++rr) {
        int v = v0 + rr;
        if (v >= V_) break;
        float acc = bg;
        #pragma unroll
        for (int e = 0; e < E_; ++e) acc = fmaf(sE[rr][e], sW[e][g], acc);
        embW[(size_t)v * 512 + c * 4 + slot] = (f16)fexp2_(acc * sc);
    }
}

// ---------------- Kernel 2: GRU, 8 waves x 16 cols, U persistent in VGPRs ----------------
// 1024 blocks x 512 threads. Block owns 16 batch rows; wave w owns h-cols
// [16w,16w+16). U slice (12 f16x8 = 48 VGPR) persistent. h XOR-swizzled LDS.
// Exp-space gates: ez = 2^rec_z * xz (table), z/r MFMA C-init = zero quad.
// Explicit 2-step unroll (named A/B register sets, both h-buffer bases static).
// MFMA 16x16x32 f16 layouts (verified rounds 2-12):
//   A: lane l holds A[l&15][(l>>4)*8 + j]
//   B: lane l holds B[(l>>4)*8 + j][l&15]
//   C/D: lane l, reg i -> row=(l>>4)*4+i, col=l&15
__global__ __launch_bounds__(512, 4) void gru_mfma_kernel(
    const int*   __restrict__ tokens,  // [B][T]
    const f16*   __restrict__ embW,    // [V][128][4] f16 exp-space
    const float* __restrict__ U,       // [128][384]
    const float* __restrict__ b,       // [2][384]
    const float* __restrict__ W1,      // [128][128]
    const float* __restrict__ b1,      // [128]
    const float* __restrict__ Wout,    // [128][3]
    const float* __restrict__ bout,    // [3]
    float* __restrict__ out)           // [B][3]
{
    __shared__ char lds[LDS_TOTAL];
    const int tid = threadIdx.x;
    const int w   = tid >> 6;       // wave = 16-col group, 0..7
    const int l   = tid & 63;
    const int cl  = l & 15;
    const int q   = l >> 4;         // 0..3
    const int R0  = blockIdx.x * 16;
    const int col = w * 16 + cl;    // this lane's h column

    // ---- stage token BYTE OFFSETS, transposed [t][r] (tok*1024 = row bytes) ----
    for (int idx = tid; idx < 16 * T_; idx += 512) {
        int r = idx >> 7, t = idx & 127;
        u32 tok = (u32)tokens[(size_t)(R0 + r) * T_ + t];
        *(u32*)(&lds[TOK_OFF + t * 64 + r * 4]) = tok * 1024u;
    }
    if (tid < 16)   // zero the t=128 prefetch row
        *(u32*)(&lds[TOK_OFF + 128 * 64 + tid * 4]) = 0u;
    // ---- zero h buffer 0 ----
    for (int idx = tid; idx < 1024; idx += 512)
        ((float*)(lds + H0_OFF))[idx] = 0.f;

    // ---- persistent U fragments, pre-scaled (one-time strided global read) ----
    f16x8 Bf[3][4];
    #pragma unroll
    for (int gt = 0; gt < 3; ++gt) {
        const float sc = (gt == 2) ? (2.f * LOG2E) : (-LOG2E);
        const int n = gt * 128 + col;
        #pragma unroll
        for (int kt = 0; kt < 4; ++kt) {
            const int k0 = kt * 32 + q * 8;
            f16x8 fr;
            #pragma unroll
            for (int j = 0; j < 8; ++j)
                fr[j] = (f16)(U[(size_t)(k0 + j) * G3_ + n] * sc);
            Bf[gt][kt] = fr;
        }
    }

    // h-gate recurrent bias (inside r*(.), can't fold into table)
    const float bhs = 2.f * LOG2E * b[G3_ + 256 + col];
    const f32x4 bh4 = {bhs, bhs, bhs, bhs};
    const f32x4 zero4 = {0.f, 0.f, 0.f, 0.f};

    float hreg[4];
    #pragma unroll
    for (int i = 0; i < 4; ++i) hreg[i] = 0.f;

    __syncthreads();

    const char* embWb = (const char*)embW;
    const int col8 = col * 8;

    // one recurrence step: read af from hb, MFMA, gates, write h to hn
    auto step = [&](const char* hb, char* hn, const u32x4& off, const f16x4* xv) {
        f16x8 af[4];
        #pragma unroll
        for (int kt = 0; kt < 4; ++kt) {
            const int chunk = (kt * 64 + q * 16) ^ ((cl & 7) << 4);
            af[kt] = *(const f16x8*)(hb + cl * 256 + chunk);
        }
        __builtin_amdgcn_s_setprio(1);
        f32x4 accz = __builtin_amdgcn_mfma_f32_16x16x32_f16(af[0], Bf[0][0], zero4, 0, 0, 0);
        f32x4 accr = __builtin_amdgcn_mfma_f32_16x16x32_f16(af[0], Bf[1][0], zero4, 0, 0, 0);
        f32x4 acch = __builtin_amdgcn_mfma_f32_16x16x32_f16(af[0], Bf[2][0], bh4,  0, 0, 0);
        accz = __builtin_amdgcn_mfma_f32_16x16x32_f16(af[1], Bf[0][1], accz, 0, 0, 0);
        accr = __builtin_amdgcn_mfma_f32_16x16x32_f16(af[1], Bf[1][1], accr, 0, 0, 0);
        acch = __builtin_amdgcn_mfma_f32_16x16x32_f16(af[1], Bf[2][1], acch, 0, 0, 0);
        accz = __builtin_amdgcn_mfma_f32_16x16x32_f16(af[2], Bf[0][2], accz, 0, 0, 0);
        accr = __builtin_amdgcn_mfma_f32_16x16x32_f16(af[2], Bf[1][2], accr, 0, 0, 0);
        acch = __builtin_amdgcn_mfma_f32_16x16x32_f16(af[2], Bf[2][2], acch, 0, 0, 0);
        accz = __builtin_amdgcn_mfma_f32_16x16x32_f16(af[3], Bf[0][3], accz, 0, 0, 0);
        accr = __builtin_amdgcn_mfma_f32_16x16x32_f16(af[3], Bf[1][3], accr, 0, 0, 0);
        acch = __builtin_amdgcn_mfma_f32_16x16x32_f16(af[3], Bf[2][3], acch, 0, 0, 0);
        __builtin_amdgcn_s_setprio(0);

        #pragma unroll
        for (int i = 0; i < 4; ++i) {
            const float ez = fexp2_(accz[i]) * (float)xv[i][0];
            const float er = fexp2_(accr[i]) * (float)xv[i][1];
            const float pz = 1.f + ez;
            const float pr = 1.f + er;
            const float inv = frcp_(pz * pr);
            const float z  = pr * inv;           // = 1/(1+ez)
            const float r  = pz * inv;           // = 1/(1+er)
            const float eh = fexp2_(r * acch[i]) * (float)xv[i][2];
            const float hh = fmaf(-2.f, frcp_(1.f + eh), 1.f);
            const float hv = hreg[i];
            float nv = fmaf(z, hv - hh, hh);
            nv = (off[i] != 0u) ? nv : hv;
            hreg[i] = nv;
            const int row = 4 * q + i;
            *(f16*)(hn + row * 256 + ((col * 2) ^ ((row & 7) << 4))) = (f16)nv;
        }
        BAR_LGKM();
    };

    // preload set A (t = 0)
    u32x4 offA = *(const u32x4*)(&lds[TOK_OFF + q * 16]);
    f16x4 xvA[4];
    #pragma unroll
    for (int i = 0; i < 4; ++i)
        xvA[i] = *(const f16x4*)(embWb + offA[i] + col8);

    for (int t = 0; t < T_; t += 2) {
        // ---- phase A (step t): buf0 -> buf1; prefetch set B (t+1) ----
        const u32x4 offB = *(const u32x4*)(&lds[TOK_OFF + (t + 1) * 64 + q * 16]);
        f16x4 xvB[4];
        #pragma unroll
        for (int i = 0; i < 4; ++i)
            xvB[i] = *(const f16x4*)(embWb + offB[i] + col8);
        step(lds + H0_OFF, lds + H1_OFF, offA, xvA);

        // ---- phase B (step t+1): buf1 -> buf0; prefetch set A (t+2) ----
        offA = *(const u32x4*)(&lds[TOK_OFF + (t + 2) * 64 + q * 16]);
        #pragma unroll
        for (int i = 0; i < 4; ++i)
            xvA[i] = *(const f16x4*)(embWb + offA[i] + col8);
        step(lds + H1_OFF, lds + H0_OFF, offB, xvB);
    }
    // T_=128 even -> final h is in buffer 0

    // ---- head: d = swish(h @ W1 + b1), one 16-col tile per wave ----
    {
        f16x8 Wf[4];
        #pragma unroll
        for (int kt = 0; kt < 4; ++kt) {
            const int k0 = kt * 32 + q * 8;
            f16x8 fr;
            #pragma unroll
            for (int j = 0; j < 8; ++j)
                fr[j] = (f16)W1[(size_t)(k0 + j) * D_ + col];
            Wf[kt] = fr;
        }
        const char* hb = lds + H0_OFF;
        const float bd = b1[col];
        f32x4 dacc = {bd, bd, bd, bd};
        #pragma unroll
        for (int kt = 0; kt < 4; ++kt) {
            const int chunk = (kt * 64 + q * 16) ^ ((cl & 7) << 4);
            const f16x8 af = *(const f16x8*)(hb + cl * 256 + chunk);
            dacc = __builtin_amdgcn_mfma_f32_16x16x32_f16(af, Wf[kt], dacc, 0, 0, 0);
        }
        #pragma unroll
        for (int i = 0; i < 4; ++i) {
            const float v = dacc[i];
            const float sw = v * frcp_(1.f + fexp2_(-LOG2E * v));
            *(float*)(&lds[DBUF_OFF + (4 * q + i) * 528 + col * 4]) = sw;
        }
    }
    __syncthreads();

    // ---- logits + softmax: wave 0, 48 lanes = 16 rows x 3 classes ----
    if (w == 0 && l < 48) {
        const int row = l & 15, ci = l >> 4;
        float acc = bout[ci];
        #pragma unroll 4
        for (int k = 0; k < D_; ++k)
            acc = fmaf(*(const float*)(&lds[DBUF_OFF + row * 528 + k * 4]),
                       Wout[k * 3 + ci], acc);
        const float v0 = __shfl(acc, row);
        const float v1 = __shfl(acc, row + 16);
        const float v2 = __shfl(acc, row + 32);
        const float mx = fmaxf(v0, fmaxf(v1, v2));
        const float e0 = fexp2_(LOG2E * (v0 - mx));
        const float e1 = fexp2_(LOG2E * (v1 - mx));
        const float e2 = fexp2_(LOG2E * (v2 - mx));
        const float inv = frcp_(e0 + e1 + e2);
        const float mine = (ci == 0) ? e0 : (ci == 1) ? e1 : e2;
        out[(size_t)(R0 + row) * 3 + ci] = mine * inv;
    }
}

extern "C" void kernel_launch(void* const* d_in, const int* in_sizes, int n_in,
                              void* d_out, int out_size, void* d_ws, size_t ws_size,
                              hipStream_t stream) {
    (void)in_sizes; (void)n_in; (void)out_size; (void)ws_size;
    const int*   tokens = (const int*)d_in[0];
    const float* emb    = (const float*)d_in[1];
    const float* W      = (const float*)d_in[2];
    const float* U      = (const float*)d_in[3];
    const float* b      = (const float*)d_in[4];
    const float* W1     = (const float*)d_in[5];
    const float* b1     = (const float*)d_in[6];
    const float* Wout   = (const float*)d_in[7];
    const float* bout   = (const float*)d_in[8];
    float* out  = (float*)d_out;
    f16*   embW = (f16*)d_ws;   // [V][128][4] f16 = 30.7 MB scratch

    hipLaunchKernelGGL(embw_kernel, dim3((V_ + K1_ROWS - 1) / K1_ROWS), dim3(384), 0, stream,
                       emb, W, b, embW);
    hipLaunchKernelGGL(gru_mfma_kernel, dim3(B_ / 16), dim3(512), 0, stream,
                       tokens, embW, U, b, W1, b1, Wout, bout, out);
}

// Round 14
// 353.013 us; speedup vs baseline: 1.4011x; 1.0083x over previous
//
#include <hip/hip_runtime.h>
#include <hip/hip_fp16.h>

#define B_ 16384
#define T_ 128
#define E_ 32
#define H_ 128
#define G3_ 384
#define V_ 30001
#define D_ 128
#define C_ 3

#define LOG2E 1.44269504088896340736f

typedef _Float16 f16;
typedef f16 f16x4 __attribute__((ext_vector_type(4)));
typedef f16 f16x8 __attribute__((ext_vector_type(8)));
typedef float f32x4 __attribute__((ext_vector_type(4)));
typedef unsigned int u32;
typedef u32 u32x4 __attribute__((ext_vector_type(4)));

// ---- LDS layout (bytes), 512-thread block, 16 batch rows ----
// h buffers: [16 rows][256 B], XOR-swizzled: byte(row,col) = row*256 + (col*2 ^ ((row&7)<<4))
#define H0_OFF   0
#define H1_OFF   4096
#define TOK_OFF  8192                // u32 byte-offsets, [t=129][r=16] (t=128 zeroed)
#define DBUF_OFF 16448               // head dbuf f32 [16][132]
#define LDS_TOTAL 24896

__device__ __forceinline__ float frcp_(float x)  { return __builtin_amdgcn_rcpf(x); }
__device__ __forceinline__ float fexp2_(float x) { return __builtin_amdgcn_exp2f(x); }

// lgkm-only barrier: orders LDS h traffic; leaves global prefetch in flight.
#define BAR_LGKM() asm volatile("s_waitcnt lgkmcnt(0)\n\ts_barrier" ::: "memory")

// ---------------- Kernel 1: packed EXP-SPACE table ----------------
// embW_p[v][c][slot] f16:
//   slot 0 = 2^(-log2e*(xz + b0z + b1z))   (z gate; v==0 row stores 0 -> z==1
//                                           -> h frozen, no mask in kernel 2)
//   slot 1 = 2^(-log2e*(xr + b0r + b1r))   (r gate, fully bias-folded)
//   slot 2 = 2^(+2log2e*(xh + b0h))        (h gate; b1h stays in-kernel)
//   slot 3 = pad
#define K1_ROWS 8
__global__ __launch_bounds__(384) void embw_kernel(
    const float* __restrict__ emb,   // [V][32]
    const float* __restrict__ W,     // [32][384]
    const float* __restrict__ b,     // [2][384]
    f16* __restrict__ embW)          // [V][128][4] f16
{
    __shared__ float sW[E_][G3_];
    __shared__ float sE[K1_ROWS][E_];
    const int g = threadIdx.x;           // 0..383 (= slot*128 + c)
    #pragma unroll
    for (int e = 0; e < E_; ++e) sW[e][g] = W[e * G3_ + g];
    const int v0 = blockIdx.x * K1_ROWS;
    for (int idx = g; idx < K1_ROWS * E_; idx += 384) {
        int rr = idx >> 5, ee = idx & 31;
        int v = v0 + rr;
        sE[rr][ee] = (v < V_) ? emb[v * E_ + ee] : 0.f;
    }
    __syncthreads();
    const float bg = b[g] + ((g < 256) ? b[G3_ + g] : 0.f);
    const int c = g & 127, slot = g >> 7;
    const float sc = (slot == 2) ? (2.f * LOG2E) : (-LOG2E);
    #pragma unroll
    for (int rr = 0; rr < K1_ROWS; ++rr) {
        int v = v0 + rr;
        if (v >= V_) break;
        float acc = bg;
        #pragma unroll
        for (int e = 0; e < E_; ++e) acc = fmaf(sE[rr][e], sW[e][g], acc);
        float val = fexp2_(acc * sc);
        if (v == 0 && slot == 0) val = 0.f;   // mask-token freeze: z -> 1
        embW[(size_t)v * 512 + c * 4 + slot] = (f16)val;
    }
}

// ---------------- Kernel 2: GRU, 8 waves x 16 cols, U persistent in VGPRs ----------------
// 1024 blocks x 512 threads. Block owns 16 batch rows; wave w owns h-cols
// [16w,16w+16). U slice (12 f16x8 = 48 VGPR) persistent. h XOR-swizzled LDS.
// Exp-space gates: pz = fma(2^rec_z, xz, 1); mask-free (z-slot trick).
// Explicit 2-step unroll (named A/B register sets, both h-buffer bases static).
// MFMA 16x16x32 f16 layouts (verified rounds 2-13):
//   A: lane l holds A[l&15][(l>>4)*8 + j]
//   B: lane l holds B[(l>>4)*8 + j][l&15]
//   C/D: lane l, reg i -> row=(l>>4)*4+i, col=l&15
__global__ __launch_bounds__(512, 4) void gru_mfma_kernel(
    const int*   __restrict__ tokens,  // [B][T]
    const f16*   __restrict__ embW,    // [V][128][4] f16 exp-space
    const float* __restrict__ U,       // [128][384]
    const float* __restrict__ b,       // [2][384]
    const float* __restrict__ W1,      // [128][128]
    const float* __restrict__ b1,      // [128]
    const float* __restrict__ Wout,    // [128][3]
    const float* __restrict__ bout,    // [3]
    float* __restrict__ out)           // [B][3]
{
    __shared__ char lds[LDS_TOTAL];
    const int tid = threadIdx.x;
    const int w   = tid >> 6;       // wave = 16-col group, 0..7
    const int l   = tid & 63;
    const int cl  = l & 15;
    const int q   = l >> 4;         // 0..3
    const int R0  = blockIdx.x * 16;
    const int col = w * 16 + cl;    // this lane's h column

    // ---- stage token BYTE OFFSETS, transposed [t][r] (tok*1024 = row bytes) ----
    for (int idx = tid; idx < 16 * T_; idx += 512) {
        int r = idx >> 7, t = idx & 127;
        u32 tok = (u32)tokens[(size_t)(R0 + r) * T_ + t];
        *(u32*)(&lds[TOK_OFF + t * 64 + r * 4]) = tok * 1024u;
    }
    if (tid < 16)   // zero the t=128 prefetch row
        *(u32*)(&lds[TOK_OFF + 128 * 64 + tid * 4]) = 0u;
    // ---- zero h buffer 0 ----
    for (int idx = tid; idx < 1024; idx += 512)
        ((float*)(lds + H0_OFF))[idx] = 0.f;

    // ---- persistent U fragments, pre-scaled (one-time strided global read) ----
    f16x8 Bf[3][4];
    #pragma unroll
    for (int gt = 0; gt < 3; ++gt) {
        const float sc = (gt == 2) ? (2.f * LOG2E) : (-LOG2E);
        const int n = gt * 128 + col;
        #pragma unroll
        for (int kt = 0; kt < 4; ++kt) {
            const int k0 = kt * 32 + q * 8;
            f16x8 fr;
            #pragma unroll
            for (int j = 0; j < 8; ++j)
                fr[j] = (f16)(U[(size_t)(k0 + j) * G3_ + n] * sc);
            Bf[gt][kt] = fr;
        }
    }

    // h-gate recurrent bias (inside r*(.), can't fold into table)
    const float bhs = 2.f * LOG2E * b[G3_ + 256 + col];
    const f32x4 bh4 = {bhs, bhs, bhs, bhs};
    const f32x4 zero4 = {0.f, 0.f, 0.f, 0.f};

    float hreg[4];
    #pragma unroll
    for (int i = 0; i < 4; ++i) hreg[i] = 0.f;

    __syncthreads();

    const char* embWb = (const char*)embW;
    const int col8 = col * 8;

    // one recurrence step: read af from hb, MFMA, gates (mask-free), write h to hn
    auto step = [&](const char* hb, char* hn, const f16x4* xv) {
        f16x8 af[4];
        #pragma unroll
        for (int kt = 0; kt < 4; ++kt) {
            const int chunk = (kt * 64 + q * 16) ^ ((cl & 7) << 4);
            af[kt] = *(const f16x8*)(hb + cl * 256 + chunk);
        }
        __builtin_amdgcn_s_setprio(1);
        f32x4 accz = __builtin_amdgcn_mfma_f32_16x16x32_f16(af[0], Bf[0][0], zero4, 0, 0, 0);
        f32x4 accr = __builtin_amdgcn_mfma_f32_16x16x32_f16(af[0], Bf[1][0], zero4, 0, 0, 0);
        f32x4 acch = __builtin_amdgcn_mfma_f32_16x16x32_f16(af[0], Bf[2][0], bh4,  0, 0, 0);
        accz = __builtin_amdgcn_mfma_f32_16x16x32_f16(af[1], Bf[0][1], accz, 0, 0, 0);
        accr = __builtin_amdgcn_mfma_f32_16x16x32_f16(af[1], Bf[1][1], accr, 0, 0, 0);
        acch = __builtin_amdgcn_mfma_f32_16x16x32_f16(af[1], Bf[2][1], acch, 0, 0, 0);
        accz = __builtin_amdgcn_mfma_f32_16x16x32_f16(af[2], Bf[0][2], accz, 0, 0, 0);
        accr = __builtin_amdgcn_mfma_f32_16x16x32_f16(af[2], Bf[1][2], accr, 0, 0, 0);
        acch = __builtin_amdgcn_mfma_f32_16x16x32_f16(af[2], Bf[2][2], acch, 0, 0, 0);
        accz = __builtin_amdgcn_mfma_f32_16x16x32_f16(af[3], Bf[0][3], accz, 0, 0, 0);
        accr = __builtin_amdgcn_mfma_f32_16x16x32_f16(af[3], Bf[1][3], accr, 0, 0, 0);
        acch = __builtin_amdgcn_mfma_f32_16x16x32_f16(af[3], Bf[2][3], acch, 0, 0, 0);
        __builtin_amdgcn_s_setprio(0);

        #pragma unroll
        for (int i = 0; i < 4; ++i) {
            const float pz = fmaf(fexp2_(accz[i]), (float)xv[i][0], 1.f);
            const float pr = fmaf(fexp2_(accr[i]), (float)xv[i][1], 1.f);
            const float inv = frcp_(pz * pr);
            const float z  = pr * inv;           // = 1/pz
            const float r  = pz * inv;           // = 1/pr
            const float ph = fmaf(fexp2_(r * acch[i]), (float)xv[i][2], 1.f);
            const float hh = fmaf(-2.f, frcp_(ph), 1.f);
            const float hv = hreg[i];
            const float nv = fmaf(z, hv - hh, hh);   // token 0: z==1 -> nv==hv
            hreg[i] = nv;
            const int row = 4 * q + i;
            *(f16*)(hn + row * 256 + ((col * 2) ^ ((row & 7) << 4))) = (f16)nv;
        }
        BAR_LGKM();
    };

    // preload set A (t = 0)
    u32x4 offA = *(const u32x4*)(&lds[TOK_OFF + q * 16]);
    f16x4 xvA[4];
    #pragma unroll
    for (int i = 0; i < 4; ++i)
        xvA[i] = *(const f16x4*)(embWb + offA[i] + col8);

    for (int t = 0; t < T_; t += 2) {
        // ---- phase A (step t): buf0 -> buf1; prefetch set B (t+1) ----
        const u32x4 offB = *(const u32x4*)(&lds[TOK_OFF + (t + 1) * 64 + q * 16]);
        f16x4 xvB[4];
        #pragma unroll
        for (int i = 0; i < 4; ++i)
            xvB[i] = *(const f16x4*)(embWb + offB[i] + col8);
        step(lds + H0_OFF, lds + H1_OFF, xvA);

        // ---- phase B (step t+1): buf1 -> buf0; prefetch set A (t+2) ----
        offA = *(const u32x4*)(&lds[TOK_OFF + (t + 2) * 64 + q * 16]);
        #pragma unroll
        for (int i = 0; i < 4; ++i)
            xvA[i] = *(const f16x4*)(embWb + offA[i] + col8);
        step(lds + H1_OFF, lds + H0_OFF, xvB);
    }
    // T_=128 even -> final h is in buffer 0

    // ---- head: d = swish(h @ W1 + b1), one 16-col tile per wave ----
    {
        f16x8 Wf[4];
        #pragma unroll
        for (int kt = 0; kt < 4; ++kt) {
            const int k0 = kt * 32 + q * 8;
            f16x8 fr;
            #pragma unroll
            for (int j = 0; j < 8; ++j)
                fr[j] = (f16)W1[(size_t)(k0 + j) * D_ + col];
            Wf[kt] = fr;
        }
        const char* hb = lds + H0_OFF;
        const float bd = b1[col];
        f32x4 dacc = {bd, bd, bd, bd};
        #pragma unroll
        for (int kt = 0; kt < 4; ++kt) {
            const int chunk = (kt * 64 + q * 16) ^ ((cl & 7) << 4);
            const f16x8 af = *(const f16x8*)(hb + cl * 256 + chunk);
            dacc = __builtin_amdgcn_mfma_f32_16x16x32_f16(af, Wf[kt], dacc, 0, 0, 0);
        }
        #pragma unroll
        for (int i = 0; i < 4; ++i) {
            const float v = dacc[i];
            const float sw = v * frcp_(1.f + fexp2_(-LOG2E * v));
            *(float*)(&lds[DBUF_OFF + (4 * q + i) * 528 + col * 4]) = sw;
        }
    }
    __syncthreads();

    // ---- logits + softmax: wave 0, 48 lanes = 16 rows x 3 classes ----
    if (w == 0 && l < 48) {
        const int row = l & 15, ci = l >> 4;
        float acc = bout[ci];
        #pragma unroll 4
        for (int k = 0; k < D_; ++k)
            acc = fmaf(*(const float*)(&lds[DBUF_OFF + row * 528 + k * 4]),
                       Wout[k * 3 + ci], acc);
        const float v0 = __shfl(acc, row);
        const float v1 = __shfl(acc, row + 16);
        const float v2 = __shfl(acc, row + 32);
        const float mx = fmaxf(v0, fmaxf(v1, v2));
        const float e0 = fexp2_(LOG2E * (v0 - mx));
        const float e1 = fexp2_(LOG2E * (v1 - mx));
        const float e2 = fexp2_(LOG2E * (v2 - mx));
        const float inv = frcp_(e0 + e1 + e2);
        const float mine = (ci == 0) ? e0 : (ci == 1) ? e1 : e2;
        out[(size_t)(R0 + row) * 3 + ci] = mine * inv;
    }
}

extern "C" void kernel_launch(void* const* d_in, const int* in_sizes, int n_in,
                              void* d_out, int out_size, void* d_ws, size_t ws_size,
                              hipStream_t stream) {
    (void)in_sizes; (void)n_in; (void)out_size; (void)ws_size;
    const int*   tokens = (const int*)d_in[0];
    const float* emb    = (const float*)d_in[1];
    const float* W      = (const float*)d_in[2];
    const float* U      = (const float*)d_in[3];
    const float* b      = (const float*)d_in[4];
    const float* W1     = (const float*)d_in[5];
    const float* b1     = (const float*)d_in[6];
    const float* Wout   = (const float*)d_in[7];
    const float* bout   = (const float*)d_in[8];
    float* out  = (float*)d_out;
    f16*   embW = (f16*)d_ws;   // [V][128][4] f16 = 30.7 MB scratch

    hipLaunchKernelGGL(embw_kernel, dim3((V_ + K1_ROWS - 1) / K1_ROWS), dim3(384), 0, stream,
                       emb, W, b, embW);
    hipLaunchKernelGGL(gru_mfma_kernel, dim3(B_ / 16), dim3(512), 0, stream,
                       tokens, embW, U, b, W1, b1, Wout, bout, out);
}

// Round 15
// 337.821 us; speedup vs baseline: 1.4641x; 1.0450x over previous
//
#include <hip/hip_runtime.h>
#include <hip/hip_fp16.h>

#define B_ 16384
#define T_ 128
#define E_ 32
#define H_ 128
#define G3_ 384
#define V_ 30001
#define D_ 128
#define C_ 3

#define LOG2E 1.44269504088896340736f

typedef _Float16 f16;
typedef f16 f16x4 __attribute__((ext_vector_type(4)));
typedef f16 f16x8 __attribute__((ext_vector_type(8)));
typedef float f32x4 __attribute__((ext_vector_type(4)));
typedef unsigned int u32;
typedef u32 u32x4 __attribute__((ext_vector_type(4)));

// ---- LDS layout (bytes), 512-thread block, 16 batch rows ----
// h buffers: [16 rows][256 B], XOR-swizzled: byte(row,col) = row*256 + (col*2 ^ ((row&7)<<4))
#define H0_OFF   0
#define H1_OFF   4096
#define TOK_OFF  8192                // u32 byte-offsets, [t=129][r=16] (t=128 zeroed)
#define DBUF_OFF 16448               // head dbuf f32 [16][132]
#define LDS_TOTAL 24896

__device__ __forceinline__ float frcp_(float x)  { return __builtin_amdgcn_rcpf(x); }
__device__ __forceinline__ float fexp2_(float x) { return __builtin_amdgcn_exp2f(x); }

// lgkm-only barrier: orders LDS h traffic; leaves global prefetch in flight.
#define BAR_LGKM() asm volatile("s_waitcnt lgkmcnt(0)\n\ts_barrier" ::: "memory")

// ---------------- Kernel 1: packed EXP-SPACE table ----------------
// embW_p[v][c][slot] f16:
//   slot 0 = 2^(-log2e*(xz + b0z + b1z))   (z gate; v==0 row stores 0 -> z==1
//                                           -> h frozen, no mask in kernel 2)
//   slot 1 = 2^(-log2e*(xr + b0r + b1r))   (r gate, fully bias-folded)
//   slot 2 = 2^(+2log2e*(xh + b0h))        (h gate; b1h stays in-kernel)
//   slot 3 = pad
#define K1_ROWS 8
__global__ __launch_bounds__(384) void embw_kernel(
    const float* __restrict__ emb,   // [V][32]
    const float* __restrict__ W,     // [32][384]
    const float* __restrict__ b,     // [2][384]
    f16* __restrict__ embW)          // [V][128][4] f16
{
    __shared__ float sW[E_][G3_];
    __shared__ float sE[K1_ROWS][E_];
    const int g = threadIdx.x;           // 0..383 (= slot*128 + c)
    #pragma unroll
    for (int e = 0; e < E_; ++e) sW[e][g] = W[e * G3_ + g];
    const int v0 = blockIdx.x * K1_ROWS;
    for (int idx = g; idx < K1_ROWS * E_; idx += 384) {
        int rr = idx >> 5, ee = idx & 31;
        int v = v0 + rr;
        sE[rr][ee] = (v < V_) ? emb[v * E_ + ee] : 0.f;
    }
    __syncthreads();
    const float bg = b[g] + ((g < 256) ? b[G3_ + g] : 0.f);
    const int c = g & 127, slot = g >> 7;
    const float sc = (slot == 2) ? (2.f * LOG2E) : (-LOG2E);
    #pragma unroll
    for (int rr = 0; rr < K1_ROWS; ++rr) {
        int v = v0 + rr;
        if (v >= V_) break;
        float acc = bg;
        #pragma unroll
        for (int e = 0; e < E_; ++e) acc = fmaf(sE[rr][e], sW[e][g], acc);
        float val = fexp2_(acc * sc);
        if (v == 0 && slot == 0) val = 0.f;   // mask-token freeze: z -> 1
        embW[(size_t)v * 512 + c * 4 + slot] = (f16)val;
    }
}

// ---------------- Kernel 2: GRU, 8 waves x 16 cols, U persistent in VGPRs ----------------
// 1024 blocks x 512 threads. Block owns 16 batch rows; wave w owns h-cols
// [16w,16w+16). U slice (12 f16x8 = 48 VGPR) persistent. h XOR-swizzled LDS.
// Exp-space gates: pz = fma(2^rec_z, xz, 1); mask-free (z-slot trick).
// Explicit 2-step unroll (named A/B register sets, static h-buffer bases).
// NO setprio: m190 evidence says it regresses barrier-lockstep structures.
// MFMA 16x16x32 f16 layouts (verified rounds 2-14):
//   A: lane l holds A[l&15][(l>>4)*8 + j]
//   B: lane l holds B[(l>>4)*8 + j][l&15]
//   C/D: lane l, reg i -> row=(l>>4)*4+i, col=l&15
__global__ __launch_bounds__(512, 4) void gru_mfma_kernel(
    const int*   __restrict__ tokens,  // [B][T]
    const f16*   __restrict__ embW,    // [V][128][4] f16 exp-space
    const float* __restrict__ U,       // [128][384]
    const float* __restrict__ b,       // [2][384]
    const float* __restrict__ W1,      // [128][128]
    const float* __restrict__ b1,      // [128]
    const float* __restrict__ Wout,    // [128][3]
    const float* __restrict__ bout,    // [3]
    float* __restrict__ out)           // [B][3]
{
    __shared__ char lds[LDS_TOTAL];
    const int tid = threadIdx.x;
    const int w   = tid >> 6;       // wave = 16-col group, 0..7
    const int l   = tid & 63;
    const int cl  = l & 15;
    const int q   = l >> 4;         // 0..3
    const int R0  = blockIdx.x * 16;
    const int col = w * 16 + cl;    // this lane's h column

    // ---- stage token BYTE OFFSETS, transposed [t][r] (tok*1024 = row bytes) ----
    for (int idx = tid; idx < 16 * T_; idx += 512) {
        int r = idx >> 7, t = idx & 127;
        u32 tok = (u32)tokens[(size_t)(R0 + r) * T_ + t];
        *(u32*)(&lds[TOK_OFF + t * 64 + r * 4]) = tok * 1024u;
    }
    if (tid < 16)   // zero the t=128 prefetch row
        *(u32*)(&lds[TOK_OFF + 128 * 64 + tid * 4]) = 0u;
    // ---- zero h buffer 0 ----
    for (int idx = tid; idx < 1024; idx += 512)
        ((float*)(lds + H0_OFF))[idx] = 0.f;

    // ---- persistent U fragments, pre-scaled (one-time strided global read) ----
    f16x8 Bf[3][4];
    #pragma unroll
    for (int gt = 0; gt < 3; ++gt) {
        const float sc = (gt == 2) ? (2.f * LOG2E) : (-LOG2E);
        const int n = gt * 128 + col;
        #pragma unroll
        for (int kt = 0; kt < 4; ++kt) {
            const int k0 = kt * 32 + q * 8;
            f16x8 fr;
            #pragma unroll
            for (int j = 0; j < 8; ++j)
                fr[j] = (f16)(U[(size_t)(k0 + j) * G3_ + n] * sc);
            Bf[gt][kt] = fr;
        }
    }

    // h-gate recurrent bias (inside r*(.), can't fold into table)
    const float bhs = 2.f * LOG2E * b[G3_ + 256 + col];
    const f32x4 bh4 = {bhs, bhs, bhs, bhs};
    const f32x4 zero4 = {0.f, 0.f, 0.f, 0.f};

    float hreg[4];
    #pragma unroll
    for (int i = 0; i < 4; ++i) hreg[i] = 0.f;

    __syncthreads();

    const char* embWb = (const char*)embW;
    const int col8 = col * 8;
    // hoisted swizzle constants
    const int rdbase = cl * 256;             // h-row byte base for A-frag reads
    const int rdxor  = (cl & 7) << 4;        // read-side XOR
    const int wr0    = (4 * q) * 256 + ((col * 2) ^ (((4 * q) & 7) << 4));
    const int wr1    = (4 * q + 1) * 256 + ((col * 2) ^ (((4 * q + 1) & 7) << 4));
    const int wr2    = (4 * q + 2) * 256 + ((col * 2) ^ (((4 * q + 2) & 7) << 4));
    const int wr3    = (4 * q + 3) * 256 + ((col * 2) ^ (((4 * q + 3) & 7) << 4));

    // one recurrence step: read af from hb, MFMA, gates (mask-free), write h to hn
    auto step = [&](const char* hb, char* hn, const f16x4* xv) {
        f16x8 af[4];
        #pragma unroll
        for (int kt = 0; kt < 4; ++kt)
            af[kt] = *(const f16x8*)(hb + rdbase + ((kt * 64 + q * 16) ^ rdxor));
        f32x4 accz = __builtin_amdgcn_mfma_f32_16x16x32_f16(af[0], Bf[0][0], zero4, 0, 0, 0);
        f32x4 accr = __builtin_amdgcn_mfma_f32_16x16x32_f16(af[0], Bf[1][0], zero4, 0, 0, 0);
        f32x4 acch = __builtin_amdgcn_mfma_f32_16x16x32_f16(af[0], Bf[2][0], bh4,  0, 0, 0);
        accz = __builtin_amdgcn_mfma_f32_16x16x32_f16(af[1], Bf[0][1], accz, 0, 0, 0);
        accr = __builtin_amdgcn_mfma_f32_16x16x32_f16(af[1], Bf[1][1], accr, 0, 0, 0);
        acch = __builtin_amdgcn_mfma_f32_16x16x32_f16(af[1], Bf[2][1], acch, 0, 0, 0);
        accz = __builtin_amdgcn_mfma_f32_16x16x32_f16(af[2], Bf[0][2], accz, 0, 0, 0);
        accr = __builtin_amdgcn_mfma_f32_16x16x32_f16(af[2], Bf[1][2], accr, 0, 0, 0);
        acch = __builtin_amdgcn_mfma_f32_16x16x32_f16(af[2], Bf[2][2], acch, 0, 0, 0);
        accz = __builtin_amdgcn_mfma_f32_16x16x32_f16(af[3], Bf[0][3], accz, 0, 0, 0);
        accr = __builtin_amdgcn_mfma_f32_16x16x32_f16(af[3], Bf[1][3], accr, 0, 0, 0);
        acch = __builtin_amdgcn_mfma_f32_16x16x32_f16(af[3], Bf[2][3], acch, 0, 0, 0);

        f16 hv16[4];
        #pragma unroll
        for (int i = 0; i < 4; ++i) {
            const float pz = fmaf(fexp2_(accz[i]), (float)xv[i][0], 1.f);
            const float pr = fmaf(fexp2_(accr[i]), (float)xv[i][1], 1.f);
            const float inv = frcp_(pz * pr);
            const float z  = pr * inv;           // = 1/pz
            const float r  = pz * inv;           // = 1/pr
            const float ph = fmaf(fexp2_(r * acch[i]), (float)xv[i][2], 1.f);
            const float hh = fmaf(-2.f, frcp_(ph), 1.f);
            const float hv = hreg[i];
            const float nv = fmaf(z, hv - hh, hh);   // token 0: z==1 -> nv==hv
            hreg[i] = nv;
            hv16[i] = (f16)nv;
        }
        *(f16*)(hn + wr0) = hv16[0];
        *(f16*)(hn + wr1) = hv16[1];
        *(f16*)(hn + wr2) = hv16[2];
        *(f16*)(hn + wr3) = hv16[3];
        BAR_LGKM();
    };

    // preload set A (t = 0)
    u32x4 offA = *(const u32x4*)(&lds[TOK_OFF + q * 16]);
    f16x4 xvA[4];
    #pragma unroll
    for (int i = 0; i < 4; ++i)
        xvA[i] = *(const f16x4*)(embWb + offA[i] + col8);

    for (int t = 0; t < T_; t += 2) {
        // ---- phase A (step t): buf0 -> buf1; prefetch set B (t+1) ----
        const u32x4 offB = *(const u32x4*)(&lds[TOK_OFF + (t + 1) * 64 + q * 16]);
        f16x4 xvB[4];
        #pragma unroll
        for (int i = 0; i < 4; ++i)
            xvB[i] = *(const f16x4*)(embWb + offB[i] + col8);
        step(lds + H0_OFF, lds + H1_OFF, xvA);

        // ---- phase B (step t+1): buf1 -> buf0; prefetch set A (t+2) ----
        offA = *(const u32x4*)(&lds[TOK_OFF + (t + 2) * 64 + q * 16]);
        #pragma unroll
        for (int i = 0; i < 4; ++i)
            xvA[i] = *(const f16x4*)(embWb + offA[i] + col8);
        step(lds + H1_OFF, lds + H0_OFF, xvB);
    }
    // T_=128 even -> final h is in buffer 0

    // ---- head: d = swish(h @ W1 + b1), one 16-col tile per wave ----
    {
        f16x8 Wf[4];
        #pragma unroll
        for (int kt = 0; kt < 4; ++kt) {
            const int k0 = kt * 32 + q * 8;
            f16x8 fr;
            #pragma unroll
            for (int j = 0; j < 8; ++j)
                fr[j] = (f16)W1[(size_t)(k0 + j) * D_ + col];
            Wf[kt] = fr;
        }
        const char* hb = lds + H0_OFF;
        const float bd = b1[col];
        f32x4 dacc = {bd, bd, bd, bd};
        #pragma unroll
        for (int kt = 0; kt < 4; ++kt) {
            const f16x8 af = *(const f16x8*)(hb + rdbase + ((kt * 64 + q * 16) ^ rdxor));
            dacc = __builtin_amdgcn_mfma_f32_16x16x32_f16(af, Wf[kt], dacc, 0, 0, 0);
        }
        #pragma unroll
        for (int i = 0; i < 4; ++i) {
            const float v = dacc[i];
            const float sw = v * frcp_(1.f + fexp2_(-LOG2E * v));
            *(float*)(&lds[DBUF_OFF + (4 * q + i) * 528 + col * 4]) = sw;
        }
    }
    __syncthreads();

    // ---- logits + softmax: wave 0, 48 lanes = 16 rows x 3 classes ----
    if (w == 0 && l < 48) {
        const int row = l & 15, ci = l >> 4;
        float acc = bout[ci];
        #pragma unroll 4
        for (int k = 0; k < D_; ++k)
            acc = fmaf(*(const float*)(&lds[DBUF_OFF + row * 528 + k * 4]),
                       Wout[k * 3 + ci], acc);
        const float v0 = __shfl(acc, row);
        const float v1 = __shfl(acc, row + 16);
        const float v2 = __shfl(acc, row + 32);
        const float mx = fmaxf(v0, fmaxf(v1, v2));
        const float e0 = fexp2_(LOG2E * (v0 - mx));
        const float e1 = fexp2_(LOG2E * (v1 - mx));
        const float e2 = fexp2_(LOG2E * (v2 - mx));
        const float inv = frcp_(e0 + e1 + e2);
        const float mine = (ci == 0) ? e0 : (ci == 1) ? e1 : e2;
        out[(size_t)(R0 + row) * 3 + ci] = mine * inv;
    }
}

extern "C" void kernel_launch(void* const* d_in, const int* in_sizes, int n_in,
                              void* d_out, int out_size, void* d_ws, size_t ws_size,
                              hipStream_t stream) {
    (void)in_sizes; (void)n_in; (void)out_size; (void)ws_size;
    const int*   tokens = (const int*)d_in[0];
    const float* emb    = (const float*)d_in[1];
    const float* W      = (const float*)d_in[2];
    const float* U      = (const float*)d_in[3];
    const float* b      = (const float*)d_in[4];
    const float* W1     = (const float*)d_in[5];
    const float* b1     = (const float*)d_in[6];
    const float* Wout   = (const float*)d_in[7];
    const float* bout   = (const float*)d_in[8];
    float* out  = (float*)d_out;
    f16*   embW = (f16*)d_ws;   // [V][128][4] f16 = 30.7 MB scratch

    hipLaunchKernelGGL(embw_kernel, dim3((V_ + K1_ROWS - 1) / K1_ROWS), dim3(384), 0, stream,
                       emb, W, b, embW);
    hipLaunchKernelGGL(gru_mfma_kernel, dim3(B_ / 16), dim3(512), 0, stream,
                       tokens, embW, U, b, W1, b1, Wout, bout, out);
}